// Round 9
// baseline (657.054 us; speedup 1.0000x reference)
//
#include <hip/hip_runtime.h>
#include <hip/hip_bf16.h>
#include <stdint.h>

// Problem: T=128, B=32, D=1024, H=1024 LSTM unroll, fp32 in/out.
#define T_STEPS 128
#define BATCH   32
#define DIM     1024
#define HID     1024
#define NGATE   4096            // 4*H
#define MROWS   4096            // T*B
#define NWGR    64              // recurrence workgroups (16 units each)
#define NGEMM   1024            // producer blocks (32 x 32 grid of 128x128 tiles)

typedef unsigned int u32;
typedef __attribute__((ext_vector_type(8)))  __bf16 bf16x8;
typedef __attribute__((ext_vector_type(4)))  float  f32x4;
typedef __attribute__((ext_vector_type(16))) float  f32x16;
typedef __attribute__((ext_vector_type(4)))  u32    u32x4;

__device__ __forceinline__ unsigned short f2bf(float f) {
    u32 x = __float_as_uint(f);
    return (unsigned short)((x + 0x7fffu + ((x >> 16) & 1u)) >> 16);  // RNE
}
__device__ __forceinline__ float sigf(float x) {
    return 1.0f / (1.0f + __expf(-x));
}
__device__ __forceinline__ float tanh_fast(float x) {
    float ax = fabsf(x);
    float e  = __expf(-2.0f * ax);           // in (0,1], no overflow
    float t  = (1.0f - e) / (1.0f + e);
    return copysignf(t, x);
}
__device__ __forceinline__ u32 umax2(u32 a, u32 b) { return a > b ? a : b; }

// DEVICE-scope (agent) ops: sc1 only. Bypass L1 + per-XCD L2, served by the
// memory-side Infinity Cache. hb AND Gp are only touched through sc1 ops
// inside lstm_fused -> no line of either ever lives in a (non-coherent) L2
// -> producer/consumer exchange is safe with no fences. (Plain stores from
// gemm blocks + sc1 polls from consumers could deadlock on stale L2 lines.)
__device__ __forceinline__ void store_u32_coh(u32* p, u32 v) {
    asm volatile("global_store_dword %0, %1, off sc1" :: "v"(p), "v"(v) : "memory");
}
__device__ __forceinline__ void store_f32_coh(float* p, float v) {
    asm volatile("global_store_dword %0, %1, off sc1" :: "v"(p), "v"(v) : "memory");
}

// ---------------- prep kernels ----------------

// sentinel fill: 0xFFFFFFFF. For hb: packed (NaN|NaN) bf16 pair -- h is finite
// in (-1,1). For Gp: fp32 -NaN with all-ones payload -- gates are bounded
// (|x@Wx+b| < ~40); real computation can never produce this bit pattern.
__global__ void fill_sentinel(u32* __restrict__ p, int n) {
    int i = (blockIdx.x * blockDim.x + threadIdx.x) * 4;
    if (i + 3 < n) {
        u32x4 v = {0xFFFFFFFFu, 0xFFFFFFFFu, 0xFFFFFFFFu, 0xFFFFFFFFu};
        *(u32x4*)(p + i) = v;
    }
}

// in: R x C fp32 (row-major) -> out: C x R bf16 with rows in GATE-MINOR
// permuted order: original col cc = g*1024 + hu  ->  out row rp = hu*4 + g.
__global__ void transpose_cast(const float* __restrict__ in,
                               unsigned short* __restrict__ out, int R, int C) {
    __shared__ float tile[32][33];
    int c0 = blockIdx.x * 32, r0 = blockIdx.y * 32;
    int tx = threadIdx.x, ty = threadIdx.y;     // 32 x 8
#pragma unroll
    for (int i = 0; i < 4; ++i)
        tile[ty + i * 8][tx] = in[(size_t)(r0 + ty + i * 8) * C + c0 + tx];
    __syncthreads();
#pragma unroll
    for (int i = 0; i < 4; ++i) {
        int cc = c0 + ty + i * 8;                       // original col (0..NGATE)
        int rp = ((cc & 1023) << 2) | (cc >> 10);       // gate-minor row
        out[(size_t)rp * R + r0 + tx] = f2bf(tile[tx][ty + i * 8]);
    }
}

// ---------------- fused kernel: GEMM producers + persistent recurrence ----------------
// Grid = NWGR + NGEMM blocks x 512 threads. Blocks 0..63 = recurrence (verbatim
// R3/R8 structure, 330us proven); blocks 64.. = gemm producers of Gp.
//
// Gp handshake (R9): Gp pre-filled with sentinel; gemm writes results via sc1;
// consumer's ga load is an sc1 load validated at USE (4 cmp + ballot ~10cy;
// retry only while the producer is behind). Single-writer, write-once,
// producers dependency-free -> deadlock-impossible; torn f32x4 caught per-word.
// Dispatch: blocks 0..63 land on CUs first; 192 CUs run gemm. Producer makes a
// 4-t-slice row-block every ~5us vs consumer's 10.3us -> ahead after startup.
// Even adversarial scheduling (gemm first) only serializes, never deadlocks.
__global__ __launch_bounds__(512, 1) void lstm_fused(
    const float* __restrict__ x,              // MROWS x DIM fp32
    const unsigned short* __restrict__ WxT,   // NGATE x DIM bf16, gate-minor rows
    const unsigned short* __restrict__ WhT,   // NGATE x DIM bf16, gate-minor rows
    const float* __restrict__ bias,           // 4H (original order)
    float* __restrict__ Gp,                   // gate-minor panels, 64 x 4096 x 64 fp32
    unsigned short* hb,                       // (T+1) x BATCH x HID bf16
    float* __restrict__ out) {                // T x BATCH x HID fp32
    // rec LDS (129 KB) + gemm LDS (16 KB) = 145 KB < 160; 1 block/CU either way
    __shared__ unsigned short Hs[32][1024];   // h tile, XOR-swizzled rows (64 KB)
    __shared__ float SlT[8][32][64];          // K-eighth partials (64 KB)
    __shared__ unsigned short Ht[32][16];     // h pack tile (1 KB)
    __shared__ unsigned short As[128 * 32];   // gemm A staging (8 KB)
    __shared__ unsigned short Bs[128 * 32];   // gemm B staging (8 KB)

    const int tid = threadIdx.x;
    const int wave = tid >> 6, lane = tid & 63;

    if (blockIdx.x >= NWGR) {
        // ================= producer: x @ Wx + b -> Gp (sc1 stores) =================
        const int g  = blockIdx.x - NWGR;
        const int bx = g & 31, by = g >> 5;        // x-fastest: all bx of by=0 first
        const int tm = by * 128, tn = bx * 128;
        const int q = lane >> 4, c = lane & 15;
        const int wm = wave >> 2, wn = wave & 3;   // 8 waves: 2 row-halves x 4 col-quarters

        f32x4 acc[4][2] = {};
        const int srow = tid >> 2;                 // 0..127
        const int scol = (tid & 3) * 8;

        float4 a0l, a0h; u32x4 rb0;
        a0l = *(const float4*)(x + (size_t)(tm + srow) * DIM + scol);
        a0h = *(const float4*)(x + (size_t)(tm + srow) * DIM + scol + 4);
        rb0 = *(const u32x4*)(WxT + (size_t)(tn + srow) * DIM + scol);

        for (int kk = 0; kk < 32; ++kk) {
            __syncthreads();
            {
                u32x4 pa = { (u32)f2bf(a0l.x) | ((u32)f2bf(a0l.y) << 16),
                             (u32)f2bf(a0l.z) | ((u32)f2bf(a0l.w) << 16),
                             (u32)f2bf(a0h.x) | ((u32)f2bf(a0h.y) << 16),
                             (u32)f2bf(a0h.z) | ((u32)f2bf(a0h.w) << 16) };
                *(u32x4*)(As + srow * 32 + scol) = pa;
                *(u32x4*)(Bs + srow * 32 + scol) = rb0;
            }
            __syncthreads();
            if (kk < 31) {
                int ko = (kk + 1) * 32 + scol;
                a0l = *(const float4*)(x + (size_t)(tm + srow) * DIM + ko);
                a0h = *(const float4*)(x + (size_t)(tm + srow) * DIM + ko + 4);
                rb0 = *(const u32x4*)(WxT + (size_t)(tn + srow) * DIM + ko);
            }
            bf16x8 af[4], bfv[2];
#pragma unroll
            for (int i = 0; i < 4; ++i)
                af[i] = *(const bf16x8*)(As + (wm * 64 + i * 16 + c) * 32 + q * 8);
#pragma unroll
            for (int j = 0; j < 2; ++j)
                bfv[j] = *(const bf16x8*)(Bs + (wn * 32 + j * 16 + c) * 32 + q * 8);
#pragma unroll
            for (int i = 0; i < 4; ++i)
#pragma unroll
                for (int j = 0; j < 2; ++j)
                    acc[i][j] = __builtin_amdgcn_mfma_f32_16x16x32_bf16(
                        af[i], bfv[j], acc[i][j], 0, 0, 0);
        }
        // epilogue: co already gate-minor (WxT row perm); bias via inverse perm.
        // sc1 scalar stores (64B-chunk coalesced across lanes c=0..15).
#pragma unroll
        for (int j = 0; j < 2; ++j) {
            int co = tn + wn * 32 + j * 16 + c;
            float bj = bias[(co & 3) * 1024 + (co >> 2)];
            int wgr = co >> 6, cp = co & 63;
#pragma unroll
            for (int i = 0; i < 4; ++i) {
                int row0 = tm + wm * 64 + i * 16 + q * 4;
#pragma unroll
                for (int r = 0; r < 4; ++r)
                    store_f32_coh(&Gp[((size_t)wgr * MROWS + row0 + r) * 64 + cp],
                                  acc[i][j][r] + bj);
            }
        }
        return;
    }

    // ================= consumer: persistent recurrence (R3 structure) =================
    const int wg = blockIdx.x;
    const int wv = wave;
    const int ln = lane & 31, lh = lane >> 5;

    // ---- stage B-fragments (Wh) into registers, once ----
    bf16x8 br0[8], br1[8];
    {
        const unsigned short* w0 =
            WhT + (size_t)(wg * 64 + ln) * DIM + wv * 128 + lh * 8;
        const unsigned short* w1 =
            WhT + (size_t)(wg * 64 + 32 + ln) * DIM + wv * 128 + lh * 8;
#pragma unroll
        for (int kk = 0; kk < 8; ++kk) {
            br0[kk] = *(const bf16x8*)(w0 + kk * 16);
            br1[kk] = *(const bf16x8*)(w1 + kk * 16);
        }
    }

    // epilogue mapping: thread = (batch, u); ONE output per thread
    const int batch = tid >> 4, uu = tid & 15;
    float cs = 0.f;

    // validated initial G load (slice 0) -- blocks until the by=0 gemm row lands
    u32x4 gau;
    {
        const float* p = Gp + ((size_t)wg * MROWS + batch) * 64 + uu * 4;
        for (;;) {
            asm volatile("global_load_dwordx4 %0, %1, off sc1\n\ts_waitcnt vmcnt(0)"
                         : "=&v"(gau) : "v"(p) : "memory");
            u32 m = umax2(umax2(gau[0], gau[1]), umax2(gau[2], gau[3]));
            if (!__any((int)(m == 0xFFFFFFFFu))) break;
        }
    }

    char* hs_base = (char*)&Hs[0][0];
    const int rxor = (ln & 15) << 4;          // read-side swizzle constant

    for (int t = 0; t < T_STEPS; ++t) {
        if (t > 0) {
            // ---- coalesced, sentinel-validated h load (wave-local retry) ----
            const char* p0 = (const char*)hb + ((size_t)t << 16)
                           + ((size_t)wv << 13) + (size_t)lane * 16;
            const char* p1 = p0 + 4096;
            u32x4 h[8];
            for (;;) {
                asm volatile(
                    "global_load_dwordx4 %0, %8, off sc1\n\t"
                    "global_load_dwordx4 %1, %8, off offset:1024 sc1\n\t"
                    "global_load_dwordx4 %2, %8, off offset:2048 sc1\n\t"
                    "global_load_dwordx4 %3, %8, off offset:3072 sc1\n\t"
                    "global_load_dwordx4 %4, %9, off sc1\n\t"
                    "global_load_dwordx4 %5, %9, off offset:1024 sc1\n\t"
                    "global_load_dwordx4 %6, %9, off offset:2048 sc1\n\t"
                    "global_load_dwordx4 %7, %9, off offset:3072 sc1\n\t"
                    "s_waitcnt vmcnt(0)"
                    : "=&v"(h[0]), "=&v"(h[1]), "=&v"(h[2]), "=&v"(h[3]),
                      "=&v"(h[4]), "=&v"(h[5]), "=&v"(h[6]), "=&v"(h[7])
                    : "v"(p0), "v"(p1)
                    : "memory");
                u32 m = 0;
#pragma unroll
                for (int i = 0; i < 8; ++i) {
                    u32 a = umax2(umax2(h[i][0], h[i][1]),
                                  umax2(h[i][2], h[i][3]));
                    m = umax2(m, a);
                }
                if (!__any((int)(m == 0xFFFFFFFFu))) break;
            }
            // ---- stage into swizzled LDS (proven R2 formula) ----
#pragma unroll
            for (int j = 0; j < 8; ++j) {
                int row  = (wv << 2) + (j >> 1);
                int colb = ((j & 1) << 10) + lane * 16;
                int off  = (row << 11) + (colb ^ ((row & 15) << 4));
                *(u32x4*)(hs_base + off) = h[j];
            }
            asm volatile("s_waitcnt lgkmcnt(0)" ::: "memory");
            __builtin_amdgcn_s_barrier();            // barrier A: Hs ready

            // ---- K-eighth: 8 A-reads, 16 MFMAs (each read feeds BOTH tiles) ----
            f32x16 acc0 = {}, acc1 = {};
            const char* hrow = hs_base + (ln << 11);
#pragma unroll
            for (int kk = 0; kk < 8; ++kk) {
                int cb = ((wv << 8) + (kk << 5) + (lh << 4)) ^ rxor;
                bf16x8 a = *(const bf16x8*)(hrow + cb);
                acc0 = __builtin_amdgcn_mfma_f32_32x32x16_bf16(a, br0[kk], acc0, 0, 0, 0);
                acc1 = __builtin_amdgcn_mfma_f32_32x32x16_bf16(a, br1[kk], acc1, 0, 0, 0);
            }

            // ---- dump partials: SlT[ks][b][col] (conflict-free) ----
#pragma unroll
            for (int rg = 0; rg < 4; ++rg)
#pragma unroll
                for (int rr = 0; rr < 4; ++rr) {
                    const int bb = rg * 8 + lh * 4 + rr;
                    SlT[wv][bb][ln]      = acc0[rg * 4 + rr];
                    SlT[wv][bb][32 + ln] = acc1[rg * 4 + rr];
                }
            asm volatile("s_waitcnt lgkmcnt(0)" ::: "memory");
            __builtin_amdgcn_s_barrier();            // barrier B: SlT ready
        }

        // ---- epilogue: validate G slice t at USE (rare retry), then gates ----
        {
            u32 m = umax2(umax2(gau[0], gau[1]), umax2(gau[2], gau[3]));
            if (__any((int)(m == 0xFFFFFFFFu))) {
                const float* p = Gp + ((size_t)wg * MROWS + (size_t)t * 32 + batch) * 64
                               + uu * 4;
                do {
                    asm volatile("global_load_dwordx4 %0, %1, off sc1\n\ts_waitcnt vmcnt(0)"
                                 : "=&v"(gau) : "v"(p) : "memory");
                    m = umax2(umax2(gau[0], gau[1]), umax2(gau[2], gau[3]));
                } while (__any((int)(m == 0xFFFFFFFFu)));
            }
        }
        f32x4 gv = __builtin_bit_cast(f32x4, gau);
        if (t > 0) {
#pragma unroll
            for (int ks = 0; ks < 8; ++ks)
                gv += *(const f32x4*)&SlT[ks][batch][uu * 4];
        }
        float cn = sigf(gv[1]) * cs + sigf(gv[0]) * tanh_fast(gv[2]);
        cs = cn;
        float hv = sigf(gv[3]) * tanh_fast(cn);

        // pack h pairs via in-wave LDS bounce, publish immediately
        Ht[batch][uu] = f2bf(hv);
        asm volatile("s_waitcnt lgkmcnt(0)" ::: "memory");
        if ((uu & 1) == 0) {
            u32 packed = *(const u32*)&Ht[batch][uu];
            store_u32_coh((u32*)(hb + (size_t)(t + 1) * (BATCH * HID)
                                    + (size_t)batch * HID + wg * 16 + uu), packed);
        }

        // off the critical path: issue G prefetch for slice t+1 (NO wait here --
        // it is drained by the next step's poll vmcnt(0), then validated at use)
        if (t + 1 < T_STEPS) {
            const float* p = Gp + ((size_t)wg * MROWS + (size_t)(t + 1) * 32 + batch) * 64
                           + uu * 4;
            asm volatile("global_load_dwordx4 %0, %1, off sc1"
                         : "=&v"(gau) : "v"(p) : "memory");
        }
        out[((size_t)t * BATCH + batch) * HID + wg * 16 + uu] = hv;
        // no end-of-loop barrier: stage(t+1) Hs writes are sentinel-gated behind
        // every wave's h-store(t+1), which follows its SlT/Hs reads of step t.
    }
}

// ---------------- launch ----------------

extern "C" void kernel_launch(void* const* d_in, const int* in_sizes, int n_in,
                              void* d_out, int out_size, void* d_ws, size_t ws_size,
                              hipStream_t stream) {
    const float* x  = (const float*)d_in[0];   // T*B*D
    const float* Wx = (const float*)d_in[1];   // D x 4H
    const float* Wh = (const float*)d_in[2];   // H x 4H
    const float* b  = (const float*)d_in[3];   // 4H
    float* out = (float*)d_out;

    // workspace layout (bytes)
    char* ws = (char*)d_ws;
    const size_t OFF_WXT  = 8ull  << 20;             // 8 MB  (gate-minor rows)
    const size_t OFF_WHT  = 16ull << 20;             // 8 MB  (gate-minor rows)
    const size_t OFF_G    = 24ull << 20;             // 64 MB (64x4096x64 fp32)
    const size_t OFF_HB   = 88ull << 20;             // 129 * 64 KB = 8.0625 MB
    const size_t NEEDED   = OFF_HB + (size_t)(T_STEPS + 1) * BATCH * HID * 2;
    if (ws_size < NEEDED) return;  // loud failure (output stays poisoned)

    unsigned short* WxT = (unsigned short*)(ws + OFF_WXT);
    unsigned short* WhT = (unsigned short*)(ws + OFF_WHT);
    float*          Gp  = (float*)(ws + OFF_G);
    unsigned short* hb  = (unsigned short*)(ws + OFF_HB);

    // prep: sentinel-fill hb AND Gp (both re-poisoned every run), transpose weights
    const int HBW = (T_STEPS + 1) * BATCH * HID / 2;         // u32 words in hb
    fill_sentinel<<<(HBW / 4 + 255) / 256, 256, 0, stream>>>((u32*)hb, HBW);
    const int GPW = NWGR * MROWS * 64;                       // u32 words in Gp (16M)
    fill_sentinel<<<(GPW / 4 + 255) / 256, 256, 0, stream>>>((u32*)Gp, GPW);
    dim3 tb(32, 8);
    transpose_cast<<<dim3(NGATE / 32, DIM / 32), tb, 0, stream>>>(Wx, WxT, DIM, NGATE);
    transpose_cast<<<dim3(NGATE / 32, HID / 32), tb, 0, stream>>>(Wh, WhT, HID, NGATE);

    // fused producer/consumer: recurrence blocks first, gemm blocks fill the rest
    lstm_fused<<<NWGR + NGEMM, 512, 0, stream>>>(x, WxT, WhT, b, Gp, hb, out);
}

// Round 10
// 468.711 us; speedup vs baseline: 1.4018x; 1.4018x over previous
//
#include <hip/hip_runtime.h>
#include <hip/hip_bf16.h>
#include <stdint.h>

// Problem: T=128, B=32, D=1024, H=1024 LSTM unroll, fp32 in/out.
#define T_STEPS 128
#define BATCH   32
#define DIM     1024
#define HID     1024
#define NGATE   4096            // 4*H
#define MROWS   4096            // T*B
#define NWGR    64              // persistent recurrence workgroups (16 units each)

typedef unsigned int u32;
typedef __attribute__((ext_vector_type(8)))  __bf16 bf16x8;
typedef __attribute__((ext_vector_type(4)))  float  f32x4;
typedef __attribute__((ext_vector_type(16))) float  f32x16;
typedef __attribute__((ext_vector_type(4)))  u32    u32x4;

__device__ __forceinline__ unsigned short f2bf(float f) {
    u32 x = __float_as_uint(f);
    return (unsigned short)((x + 0x7fffu + ((x >> 16) & 1u)) >> 16);  // RNE
}
__device__ __forceinline__ float sigf(float x) {
    return 1.0f / (1.0f + __expf(-x));
}
__device__ __forceinline__ float tanh_fast(float x) {
    float ax = fabsf(x);
    float e  = __expf(-2.0f * ax);           // in (0,1], no overflow
    float t  = (1.0f - e) / (1.0f + e);
    return copysignf(t, x);
}
__device__ __forceinline__ u32 umax2(u32 a, u32 b) { return a > b ? a : b; }

// DEVICE-scope (agent) store: sc1 only. Bypasses L1 + per-XCD L2, served by
// the memory-side Infinity Cache. hb is ONLY touched through sc1 ops during
// lstm_rec -> no line of it ever lives in any L2 -> no fences needed.
__device__ __forceinline__ void store_u32_coh(u32* p, u32 v) {
    asm volatile("global_store_dword %0, %1, off sc1" :: "v"(p), "v"(v) : "memory");
}

// async global->LDS, 16B per lane: HW writes LDS at wave-uniform base + lane*16.
__device__ __forceinline__ void gload16(void* lds, const void* g) {
    __builtin_amdgcn_global_load_lds(
        (const __attribute__((address_space(1))) unsigned int*)g,
        (__attribute__((address_space(3))) unsigned int*)lds, 16, 0, 0);
}

// ---------------- prep kernels ----------------

__global__ void cast_f32_bf16(const float* __restrict__ in,
                              unsigned short* __restrict__ out, int n) {
    int idx = (blockIdx.x * blockDim.x + threadIdx.x) * 4;
    if (idx + 3 < n) {
        float4 v = *(const float4*)(in + idx);
        ushort4 o;
        o.x = f2bf(v.x); o.y = f2bf(v.y); o.z = f2bf(v.z); o.w = f2bf(v.w);
        *(ushort4*)(out + idx) = o;
    }
}

// sentinel fill: 0xFFFFFFFF = packed (NaN|NaN) bf16 pair; h is always finite
// and in (-1,1), so a real packed h can never equal the sentinel.
__global__ void fill_sentinel(u32* __restrict__ p, int n) {
    int i = (blockIdx.x * blockDim.x + threadIdx.x) * 4;
    if (i + 3 < n) {
        u32x4 v = {0xFFFFFFFFu, 0xFFFFFFFFu, 0xFFFFFFFFu, 0xFFFFFFFFu};
        *(u32x4*)(p + i) = v;
    }
}

// in: R x C fp32 (row-major) -> out: C x R bf16 with rows in GATE-MINOR
// permuted order: original col cc = g*1024 + hu  ->  out row rp = hu*4 + g.
__global__ void transpose_cast(const float* __restrict__ in,
                               unsigned short* __restrict__ out, int R, int C) {
    __shared__ float tile[32][33];
    int c0 = blockIdx.x * 32, r0 = blockIdx.y * 32;
    int tx = threadIdx.x, ty = threadIdx.y;     // 32 x 8
#pragma unroll
    for (int i = 0; i < 4; ++i)
        tile[ty + i * 8][tx] = in[(size_t)(r0 + ty + i * 8) * C + c0 + tx];
    __syncthreads();
#pragma unroll
    for (int i = 0; i < 4; ++i) {
        int cc = c0 + ty + i * 8;                       // original col (0..NGATE)
        int rp = ((cc & 1023) << 2) | (cc >> 10);       // gate-minor row
        out[(size_t)rp * R + r0 + tx] = f2bf(tile[tx][ty + i * 8]);
    }
}

// ---------------- phase 1: Gp = perm(x @ Wx + b)  (m97-structure GEMM) ----------------
// A: MROWS x DIM bf16 (pre-cast x), BT: NGATE x DIM bf16 gate-minor rows.
// R10: staging via global_load_lds width=16 (async, no VGPR round-trip, no
// packing VALU -- the R8 reg-staged+cast version was ~264 TF; the m97 recipe
// reaches ~874 at this tile geometry). Fragment reads, MFMA block, and the
// coalesced gate-minor epilogue are byte-identical to R8's verified code.
// LDS 16 KB -> multiple blocks/CU.
__global__ __launch_bounds__(256) void gemm_xw(
    const unsigned short* __restrict__ A,
    const unsigned short* __restrict__ BT,
    const float* __restrict__ bias,
    float* __restrict__ Gp) {
    __shared__ unsigned short As[128 * 32];
    __shared__ unsigned short Bs[128 * 32];
    const int tid = threadIdx.x;
    const int wv = tid >> 6, lane = tid & 63;
    const int q = lane >> 4, c = lane & 15;
    const int wm = wv >> 1, wn = wv & 1;
    const int tm = blockIdx.y * 128, tn = blockIdx.x * 128;

    f32x4 acc[4][4] = {};

    // staging geometry: chunk = wv*2+i covers 16 rows (1 KB); lane l handles
    // row chunk*16 + l/4, byte col (l&3)*16 -> LDS linear chunk*1024 + l*16.
    const int rA = (wv * 2) * 16 + (lane >> 2);
    const int cb = (lane & 3) * 16;
    const char* gA0 = (const char*)A  + (size_t)(tm + rA) * (DIM * 2) + cb;
    const char* gA1 = gA0 + (size_t)16 * DIM * 2;
    const char* gB0 = (const char*)BT + (size_t)(tn + rA) * (DIM * 2) + cb;
    const char* gB1 = gB0 + (size_t)16 * DIM * 2;
    char* lA0 = (char*)As + (wv * 2 + 0) * 1024;
    char* lA1 = (char*)As + (wv * 2 + 1) * 1024;
    char* lB0 = (char*)Bs + (wv * 2 + 0) * 1024;
    char* lB1 = (char*)Bs + (wv * 2 + 1) * 1024;

    for (int kk = 0; kk < 32; ++kk) {
        const size_t ko = (size_t)kk * 64;              // byte offset along K
        __syncthreads();                                // prev reads done
        gload16(lA0, gA0 + ko);
        gload16(lA1, gA1 + ko);
        gload16(lB0, gB0 + ko);
        gload16(lB1, gB1 + ko);
        __syncthreads();                                // vmcnt(0) drain + barrier
        bf16x8 af[4], bfv[4];
#pragma unroll
        for (int i = 0; i < 4; ++i) {
            af[i]  = *(const bf16x8*)(As + (wm * 64 + i * 16 + c) * 32 + q * 8);
            bfv[i] = *(const bf16x8*)(Bs + (wn * 64 + i * 16 + c) * 32 + q * 8);
        }
#pragma unroll
        for (int i = 0; i < 4; ++i)
#pragma unroll
            for (int j = 0; j < 4; ++j)
                acc[i][j] = __builtin_amdgcn_mfma_f32_16x16x32_bf16(
                    af[i], bfv[j], acc[i][j], 0, 0, 0);
    }
    // epilogue (R8, verified): co already gate-minor; bias via inverse perm;
    // lanes c=0..15 write 16 consecutive floats -> coalesced 64B chunks.
#pragma unroll
    for (int j = 0; j < 4; ++j) {
        int co = tn + wn * 64 + j * 16 + c;             // gate-minor col hu*4+g
        float bj = bias[(co & 3) * 1024 + (co >> 2)];
        int wgr = co >> 6, cp = co & 63;
#pragma unroll
        for (int i = 0; i < 4; ++i) {
            int row0 = tm + wm * 64 + i * 16 + q * 4;
#pragma unroll
            for (int r = 0; r < 4; ++r)
                Gp[((size_t)wgr * MROWS + row0 + r) * 64 + cp] = acc[i][j][r] + bj;
        }
    }
}

// ---------------- phase 2: persistent recurrence (EXACT R3/R8 structure, 327us) ----------------
__global__ __launch_bounds__(512, 1) void lstm_rec(
    const unsigned short* __restrict__ WhT,   // NGATE x DIM bf16, gate-minor rows
    const float* __restrict__ Gp,             // gate-minor panels, 64 x 4096 x 64 fp32
    unsigned short* hb,                       // (T+1) x BATCH x HID bf16 (slot 0 unused)
    float* __restrict__ out) {                // T x BATCH x HID fp32
    __shared__ unsigned short Hs[32][1024];   // h tile, XOR-swizzled rows (64 KB)
    __shared__ float SlT[8][32][64];          // K-eighth partials [ks][b][panel col] (64 KB)
    __shared__ unsigned short Ht[32][16];     // h bf16 pack tile (1 KB)
    const int wg = blockIdx.x, tid = threadIdx.x;
    const int wv = tid >> 6, lane = tid & 63;
    const int ln = lane & 31, lh = lane >> 5;

    // ---- stage B-fragments (Wh) into registers, once ----
    bf16x8 br0[8], br1[8];
    {
        const unsigned short* w0 =
            WhT + (size_t)(wg * 64 + ln) * DIM + wv * 128 + lh * 8;
        const unsigned short* w1 =
            WhT + (size_t)(wg * 64 + 32 + ln) * DIM + wv * 128 + lh * 8;
#pragma unroll
        for (int kk = 0; kk < 8; ++kk) {
            br0[kk] = *(const bf16x8*)(w0 + kk * 16);
            br1[kk] = *(const bf16x8*)(w1 + kk * 16);
        }
    }

    // epilogue mapping: thread = (batch, u); ONE output per thread
    const int batch = tid >> 4, uu = tid & 15;
    float cs = 0.f;
    // G prefetch for t=0 (gate-minor: f32x4 = 4 gates of unit uu)
    f32x4 ga = *(const f32x4*)(Gp + ((size_t)wg * MROWS + batch) * 64 + uu * 4);

    char* hs_base = (char*)&Hs[0][0];
    const int rxor = (ln & 15) << 4;          // read-side swizzle constant

    for (int t = 0; t < T_STEPS; ++t) {
        if (t > 0) {
            // ---- coalesced, sentinel-validated h load (wave-local retry) ----
            const char* p0 = (const char*)hb + ((size_t)t << 16)
                           + ((size_t)wv << 13) + (size_t)lane * 16;
            const char* p1 = p0 + 4096;
            u32x4 h[8];
            for (;;) {
                asm volatile(
                    "global_load_dwordx4 %0, %8, off sc1\n\t"
                    "global_load_dwordx4 %1, %8, off offset:1024 sc1\n\t"
                    "global_load_dwordx4 %2, %8, off offset:2048 sc1\n\t"
                    "global_load_dwordx4 %3, %8, off offset:3072 sc1\n\t"
                    "global_load_dwordx4 %4, %9, off sc1\n\t"
                    "global_load_dwordx4 %5, %9, off offset:1024 sc1\n\t"
                    "global_load_dwordx4 %6, %9, off offset:2048 sc1\n\t"
                    "global_load_dwordx4 %7, %9, off offset:3072 sc1\n\t"
                    "s_waitcnt vmcnt(0)"
                    : "=&v"(h[0]), "=&v"(h[1]), "=&v"(h[2]), "=&v"(h[3]),
                      "=&v"(h[4]), "=&v"(h[5]), "=&v"(h[6]), "=&v"(h[7])
                    : "v"(p0), "v"(p1)
                    : "memory");
                u32 m = 0;
#pragma unroll
                for (int i = 0; i < 8; ++i) {
                    u32 a = umax2(umax2(h[i][0], h[i][1]),
                                  umax2(h[i][2], h[i][3]));
                    m = umax2(m, a);
                }
                if (!__any((int)(m == 0xFFFFFFFFu))) break;
            }
            // ---- stage into swizzled LDS (proven R2 formula) ----
#pragma unroll
            for (int j = 0; j < 8; ++j) {
                int row  = (wv << 2) + (j >> 1);
                int colb = ((j & 1) << 10) + lane * 16;
                int off  = (row << 11) + (colb ^ ((row & 15) << 4));
                *(u32x4*)(hs_base + off) = h[j];
            }
            asm volatile("s_waitcnt lgkmcnt(0)" ::: "memory");
            __builtin_amdgcn_s_barrier();            // barrier A: Hs ready

            // ---- K-eighth: 8 A-reads, 16 MFMAs (each read feeds BOTH tiles) ----
            f32x16 acc0 = {}, acc1 = {};
            const char* hrow = hs_base + (ln << 11);
#pragma unroll
            for (int kk = 0; kk < 8; ++kk) {
                int cb = ((wv << 8) + (kk << 5) + (lh << 4)) ^ rxor;
                bf16x8 a = *(const bf16x8*)(hrow + cb);
                acc0 = __builtin_amdgcn_mfma_f32_32x32x16_bf16(a, br0[kk], acc0, 0, 0, 0);
                acc1 = __builtin_amdgcn_mfma_f32_32x32x16_bf16(a, br1[kk], acc1, 0, 0, 0);
            }

            // ---- dump partials: SlT[ks][b][col] (conflict-free) ----
#pragma unroll
            for (int rg = 0; rg < 4; ++rg)
#pragma unroll
                for (int rr = 0; rr < 4; ++rr) {
                    const int bb = rg * 8 + lh * 4 + rr;
                    SlT[wv][bb][ln]      = acc0[rg * 4 + rr];
                    SlT[wv][bb][32 + ln] = acc1[rg * 4 + rr];
                }
            asm volatile("s_waitcnt lgkmcnt(0)" ::: "memory");
            __builtin_amdgcn_s_barrier();            // barrier B: SlT ready
        }

        // ---- epilogue: ONE output (batch, unit uu) per thread ----
        f32x4 gv = ga;                               // gates i,f,g,o of unit uu
        if (t > 0) {
#pragma unroll
            for (int ks = 0; ks < 8; ++ks)
                gv += *(const f32x4*)&SlT[ks][batch][uu * 4];
        }
        float cn = sigf(gv[1]) * cs + sigf(gv[0]) * tanh_fast(gv[2]);
        cs = cn;
        float hv = sigf(gv[3]) * tanh_fast(cn);

        // pack h pairs via in-wave LDS bounce (Ht rows 4b per wave: in-wave only)
        Ht[batch][uu] = f2bf(hv);
        asm volatile("s_waitcnt lgkmcnt(0)" ::: "memory");
        if ((uu & 1) == 0) {
            u32 packed = *(const u32*)&Ht[batch][uu];
            store_u32_coh((u32*)(hb + (size_t)(t + 1) * (BATCH * HID)
                                    + (size_t)batch * HID + wg * 16 + uu), packed);
        }

        // off the critical path: G prefetch for step t+1 + out-store
        if (t + 1 < T_STEPS)
            ga = *(const f32x4*)(Gp + ((size_t)wg * MROWS + (size_t)(t + 1) * 32 + batch) * 64
                                 + uu * 4);
        out[((size_t)t * BATCH + batch) * HID + wg * 16 + uu] = hv;
        // no end-of-loop barrier: stage(t+1) Hs writes are sentinel-gated behind
        // every wave's h-store(t+1), which follows its SlT/Hs reads of step t.
    }
}

// ---------------- launch ----------------

extern "C" void kernel_launch(void* const* d_in, const int* in_sizes, int n_in,
                              void* d_out, int out_size, void* d_ws, size_t ws_size,
                              hipStream_t stream) {
    const float* x  = (const float*)d_in[0];   // T*B*D
    const float* Wx = (const float*)d_in[1];   // D x 4H
    const float* Wh = (const float*)d_in[2];   // H x 4H
    const float* b  = (const float*)d_in[3];   // 4H
    float* out = (float*)d_out;

    // workspace layout (bytes)
    char* ws = (char*)d_ws;
    const size_t OFF_XBF  = 0;                       // 8 MB  (4096x1024 bf16)
    const size_t OFF_WXT  = 8ull  << 20;             // 8 MB  (gate-minor rows)
    const size_t OFF_WHT  = 16ull << 20;             // 8 MB  (gate-minor rows)
    const size_t OFF_G    = 24ull << 20;             // 64 MB (64x4096x64 fp32)
    const size_t OFF_HB   = 88ull << 20;             // 129 * 64 KB = 8.0625 MB
    const size_t NEEDED   = OFF_HB + (size_t)(T_STEPS + 1) * BATCH * HID * 2;
    if (ws_size < NEEDED) return;  // loud failure (output stays poisoned)

    unsigned short* xbf = (unsigned short*)(ws + OFF_XBF);
    unsigned short* WxT = (unsigned short*)(ws + OFF_WXT);
    unsigned short* WhT = (unsigned short*)(ws + OFF_WHT);
    float*          Gp  = (float*)(ws + OFF_G);
    unsigned short* hb  = (unsigned short*)(ws + OFF_HB);

    // prep
    cast_f32_bf16<<<(MROWS * DIM / 4 + 255) / 256, 256, 0, stream>>>(x, xbf, MROWS * DIM);
    const int HBW = (T_STEPS + 1) * BATCH * HID / 2;    // u32 words in hb
    fill_sentinel<<<(HBW / 4 + 255) / 256, 256, 0, stream>>>((u32*)hb, HBW);
    dim3 tb(32, 8);
    transpose_cast<<<dim3(NGATE / 32, DIM / 32), tb, 0, stream>>>(Wx, WxT, DIM, NGATE);
    transpose_cast<<<dim3(NGATE / 32, HID / 32), tb, 0, stream>>>(Wh, WhT, HID, NGATE);

    // phase 1: all-timestep input GEMM (async-staged, gate-minor coalesced output)
    gemm_xw<<<dim3(NGATE / 128, MROWS / 128), 256, 0, stream>>>(xbf, WxT, b, Gp);

    // phase 2: persistent recurrence (exact R3/R8 structure)
    lstm_rec<<<NWGR, 512, 0, stream>>>(WhT, Gp, hb, out);
}

// Round 11
// 464.286 us; speedup vs baseline: 1.4152x; 1.0095x over previous
//
#include <hip/hip_runtime.h>
#include <hip/hip_bf16.h>
#include <stdint.h>

// Problem: T=128, B=32, D=1024, H=1024 LSTM unroll, fp32 in/out.
#define T_STEPS 128
#define BATCH   32
#define DIM     1024
#define HID     1024
#define NGATE   4096            // 4*H
#define MROWS   4096            // T*B
#define NWGR    64              // persistent recurrence workgroups (16 units each)

typedef unsigned int u32;
typedef __attribute__((ext_vector_type(8)))  __bf16 bf16x8;
typedef __attribute__((ext_vector_type(4)))  float  f32x4;
typedef __attribute__((ext_vector_type(16))) float  f32x16;
typedef __attribute__((ext_vector_type(4)))  u32    u32x4;

__device__ __forceinline__ unsigned short f2bf(float f) {
    u32 x = __float_as_uint(f);
    return (unsigned short)((x + 0x7fffu + ((x >> 16) & 1u)) >> 16);  // RNE
}
__device__ __forceinline__ float sigf(float x) {
    return 1.0f / (1.0f + __expf(-x));
}
__device__ __forceinline__ float tanh_fast(float x) {
    float ax = fabsf(x);
    float e  = __expf(-2.0f * ax);           // in (0,1], no overflow
    float t  = (1.0f - e) / (1.0f + e);
    return copysignf(t, x);
}
__device__ __forceinline__ u32 umax2(u32 a, u32 b) { return a > b ? a : b; }

// DEVICE-scope (agent) store: sc1 only. Bypasses L1 + per-XCD L2, served by
// the memory-side Infinity Cache. hb is ONLY touched through sc1 ops during
// lstm_rec -> no line of it ever lives in any L2 -> no fences needed.
__device__ __forceinline__ void store_u32_coh(u32* p, u32 v) {
    asm volatile("global_store_dword %0, %1, off sc1" :: "v"(p), "v"(v) : "memory");
}

// async global->LDS, 16B per lane: HW writes LDS at wave-uniform base + lane*16.
__device__ __forceinline__ void gload16(void* lds, const void* g) {
    __builtin_amdgcn_global_load_lds(
        (const __attribute__((address_space(1))) unsigned int*)g,
        (__attribute__((address_space(3))) unsigned int*)lds, 16, 0, 0);
}

// ---------------- merged prep kernel (R11: 4 launches -> 1) ----------------
// Block ranges (all jobs independent; one launch removes 3 dispatch gaps +
// 3 full-device tail drains of the old serial mini-kernel chain):
//   [0, 2048)       cast x fp32->bf16 (8 elems/thread)
//   [2048, 4112)    sentinel-fill hb (0xFFFFFFFF = NaN|NaN bf16 pair; h is
//                   finite in (-1,1) so a real packed h can never equal it)
//   [4112, 8208)    transpose_cast Wx -> WxT (gate-minor rows)
//   [8208, 12304)   transpose_cast Wh -> WhT (gate-minor rows)
#define PREP_CAST0   0
#define PREP_FILL0   2048
#define PREP_TWX0    4112
#define PREP_TWH0    8208
#define PREP_NBLK    12304

__global__ __launch_bounds__(256) void prep_all(
    const float* __restrict__ x,  unsigned short* __restrict__ xbf,
    u32* __restrict__ hbw, int nhb,
    const float* __restrict__ Wx, unsigned short* __restrict__ WxT,
    const float* __restrict__ Wh, unsigned short* __restrict__ WhT) {
    __shared__ float tile[32][33];
    const int b = blockIdx.x, tid = threadIdx.x;

    if (b < PREP_FILL0) {
        // ---- cast x: 8 floats -> 8 bf16 per thread ----
        const int idx = ((b - PREP_CAST0) * 256 + tid) * 8;
        float4 v0 = *(const float4*)(x + idx);
        float4 v1 = *(const float4*)(x + idx + 4);
        u32x4 o = { (u32)f2bf(v0.x) | ((u32)f2bf(v0.y) << 16),
                    (u32)f2bf(v0.z) | ((u32)f2bf(v0.w) << 16),
                    (u32)f2bf(v1.x) | ((u32)f2bf(v1.y) << 16),
                    (u32)f2bf(v1.z) | ((u32)f2bf(v1.w) << 16) };
        *(u32x4*)(xbf + idx) = o;
    } else if (b < PREP_TWX0) {
        // ---- sentinel-fill hb ----
        const int i = ((b - PREP_FILL0) * 256 + tid) * 4;
        if (i + 3 < nhb) {
            u32x4 v = {0xFFFFFFFFu, 0xFFFFFFFFu, 0xFFFFFFFFu, 0xFFFFFFFFu};
            *(u32x4*)(hbw + i) = v;
        }
    } else {
        // ---- transpose_cast: in R=1024 x C=4096 fp32 -> out 4096 x 1024 bf16,
        // rows gate-minor permuted: orig col cc = g*1024+hu -> row hu*4+g ----
        const int which = (b >= PREP_TWH0);
        const int g2 = which ? (b - PREP_TWH0) : (b - PREP_TWX0);   // 0..4095
        const float* in = which ? Wh : Wx;
        unsigned short* outp = which ? WhT : WxT;
        const int bx2 = g2 & 127, by2 = g2 >> 7;     // old grid (128, 32)
        const int c0 = bx2 * 32, r0 = by2 * 32;
        const int tx = tid & 31, ty = tid >> 5;      // 32 x 8
#pragma unroll
        for (int i = 0; i < 4; ++i)
            tile[ty + i * 8][tx] = in[(size_t)(r0 + ty + i * 8) * NGATE + c0 + tx];
        __syncthreads();
#pragma unroll
        for (int i = 0; i < 4; ++i) {
            int cc = c0 + ty + i * 8;                    // original col (0..NGATE)
            int rp = ((cc & 1023) << 2) | (cc >> 10);    // gate-minor row
            outp[(size_t)rp * DIM + r0 + tx] = f2bf(tile[tx][ty + i * 8]);
        }
    }
}

// ---------------- phase 1: Gp = perm(x @ Wx + b)  (m97-structure GEMM) ----------------
// A: MROWS x DIM bf16 (pre-cast x), BT: NGATE x DIM bf16 gate-minor rows.
// Staging via global_load_lds width=16 (R10, kept). R11 adds the T1
// XCD-chunked bijective block swizzle (nwg=1024, 1024%8==0): each XCD gets
// 4 contiguous by-rows x 32 bx -> A-panel working set 1MB (L2-resident)
// instead of 8MB thrash; B streams from IC. Perf-only, mapping-independent.
__global__ __launch_bounds__(256) void gemm_xw(
    const unsigned short* __restrict__ A,
    const unsigned short* __restrict__ BT,
    const float* __restrict__ bias,
    float* __restrict__ Gp) {
    __shared__ unsigned short As[128 * 32];
    __shared__ unsigned short Bs[128 * 32];
    const int tid = threadIdx.x;
    const int wv = tid >> 6, lane = tid & 63;
    const int q = lane >> 4, c = lane & 15;
    const int wm = wv >> 1, wn = wv & 1;
    // T1 swizzle: bid -> contiguous 128-block chunk per XCD (bid%8 presumed XCD)
    const int bid  = blockIdx.y * 32 + blockIdx.x;
    const int wgid = (bid & 7) * 128 + (bid >> 3);
    const int tm = (wgid >> 5) * 128, tn = (wgid & 31) * 128;

    f32x4 acc[4][4] = {};

    // staging geometry: chunk = wv*2+i covers 16 rows (1 KB); lane l handles
    // row chunk*16 + l/4, byte col (l&3)*16 -> LDS linear chunk*1024 + l*16.
    const int rA = (wv * 2) * 16 + (lane >> 2);
    const int cb = (lane & 3) * 16;
    const char* gA0 = (const char*)A  + (size_t)(tm + rA) * (DIM * 2) + cb;
    const char* gA1 = gA0 + (size_t)16 * DIM * 2;
    const char* gB0 = (const char*)BT + (size_t)(tn + rA) * (DIM * 2) + cb;
    const char* gB1 = gB0 + (size_t)16 * DIM * 2;
    char* lA0 = (char*)As + (wv * 2 + 0) * 1024;
    char* lA1 = (char*)As + (wv * 2 + 1) * 1024;
    char* lB0 = (char*)Bs + (wv * 2 + 0) * 1024;
    char* lB1 = (char*)Bs + (wv * 2 + 1) * 1024;

    for (int kk = 0; kk < 32; ++kk) {
        const size_t ko = (size_t)kk * 64;              // byte offset along K
        __syncthreads();                                // prev reads done
        gload16(lA0, gA0 + ko);
        gload16(lA1, gA1 + ko);
        gload16(lB0, gB0 + ko);
        gload16(lB1, gB1 + ko);
        __syncthreads();                                // vmcnt(0) drain + barrier
        bf16x8 af[4], bfv[4];
#pragma unroll
        for (int i = 0; i < 4; ++i) {
            af[i]  = *(const bf16x8*)(As + (wm * 64 + i * 16 + c) * 32 + q * 8);
            bfv[i] = *(const bf16x8*)(Bs + (wn * 64 + i * 16 + c) * 32 + q * 8);
        }
#pragma unroll
        for (int i = 0; i < 4; ++i)
#pragma unroll
            for (int j = 0; j < 4; ++j)
                acc[i][j] = __builtin_amdgcn_mfma_f32_16x16x32_bf16(
                    af[i], bfv[j], acc[i][j], 0, 0, 0);
    }
    // epilogue (R8, verified): co already gate-minor; bias via inverse perm;
    // lanes c=0..15 write 16 consecutive floats -> coalesced 64B chunks.
#pragma unroll
    for (int j = 0; j < 4; ++j) {
        int co = tn + wn * 64 + j * 16 + c;             // gate-minor col hu*4+g
        float bj = bias[(co & 3) * 1024 + (co >> 2)];
        int wgr = co >> 6, cp = co & 63;
#pragma unroll
        for (int i = 0; i < 4; ++i) {
            int row0 = tm + wm * 64 + i * 16 + q * 4;
#pragma unroll
            for (int r = 0; r < 4; ++r)
                Gp[((size_t)wgr * MROWS + row0 + r) * 64 + cp] = acc[i][j][r] + bj;
        }
    }
}

// ---------------- phase 2: persistent recurrence (EXACT R3/R8/R10 structure, 327us) ----------------
__global__ __launch_bounds__(512, 1) void lstm_rec(
    const unsigned short* __restrict__ WhT,   // NGATE x DIM bf16, gate-minor rows
    const float* __restrict__ Gp,             // gate-minor panels, 64 x 4096 x 64 fp32
    unsigned short* hb,                       // (T+1) x BATCH x HID bf16 (slot 0 unused)
    float* __restrict__ out) {                // T x BATCH x HID fp32
    __shared__ unsigned short Hs[32][1024];   // h tile, XOR-swizzled rows (64 KB)
    __shared__ float SlT[8][32][64];          // K-eighth partials [ks][b][panel col] (64 KB)
    __shared__ unsigned short Ht[32][16];     // h bf16 pack tile (1 KB)
    const int wg = blockIdx.x, tid = threadIdx.x;
    const int wv = tid >> 6, lane = tid & 63;
    const int ln = lane & 31, lh = lane >> 5;

    // ---- stage B-fragments (Wh) into registers, once ----
    bf16x8 br0[8], br1[8];
    {
        const unsigned short* w0 =
            WhT + (size_t)(wg * 64 + ln) * DIM + wv * 128 + lh * 8;
        const unsigned short* w1 =
            WhT + (size_t)(wg * 64 + 32 + ln) * DIM + wv * 128 + lh * 8;
#pragma unroll
        for (int kk = 0; kk < 8; ++kk) {
            br0[kk] = *(const bf16x8*)(w0 + kk * 16);
            br1[kk] = *(const bf16x8*)(w1 + kk * 16);
        }
    }

    // epilogue mapping: thread = (batch, u); ONE output per thread
    const int batch = tid >> 4, uu = tid & 15;
    float cs = 0.f;
    // G prefetch for t=0 (gate-minor: f32x4 = 4 gates of unit uu)
    f32x4 ga = *(const f32x4*)(Gp + ((size_t)wg * MROWS + batch) * 64 + uu * 4);

    char* hs_base = (char*)&Hs[0][0];
    const int rxor = (ln & 15) << 4;          // read-side swizzle constant

    for (int t = 0; t < T_STEPS; ++t) {
        if (t > 0) {
            // ---- coalesced, sentinel-validated h load (wave-local retry) ----
            const char* p0 = (const char*)hb + ((size_t)t << 16)
                           + ((size_t)wv << 13) + (size_t)lane * 16;
            const char* p1 = p0 + 4096;
            u32x4 h[8];
            for (;;) {
                asm volatile(
                    "global_load_dwordx4 %0, %8, off sc1\n\t"
                    "global_load_dwordx4 %1, %8, off offset:1024 sc1\n\t"
                    "global_load_dwordx4 %2, %8, off offset:2048 sc1\n\t"
                    "global_load_dwordx4 %3, %8, off offset:3072 sc1\n\t"
                    "global_load_dwordx4 %4, %9, off sc1\n\t"
                    "global_load_dwordx4 %5, %9, off offset:1024 sc1\n\t"
                    "global_load_dwordx4 %6, %9, off offset:2048 sc1\n\t"
                    "global_load_dwordx4 %7, %9, off offset:3072 sc1\n\t"
                    "s_waitcnt vmcnt(0)"
                    : "=&v"(h[0]), "=&v"(h[1]), "=&v"(h[2]), "=&v"(h[3]),
                      "=&v"(h[4]), "=&v"(h[5]), "=&v"(h[6]), "=&v"(h[7])
                    : "v"(p0), "v"(p1)
                    : "memory");
                u32 m = 0;
#pragma unroll
                for (int i = 0; i < 8; ++i) {
                    u32 a = umax2(umax2(h[i][0], h[i][1]),
                                  umax2(h[i][2], h[i][3]));
                    m = umax2(m, a);
                }
                if (!__any((int)(m == 0xFFFFFFFFu))) break;
            }
            // ---- stage into swizzled LDS (proven R2 formula) ----
#pragma unroll
            for (int j = 0; j < 8; ++j) {
                int row  = (wv << 2) + (j >> 1);
                int colb = ((j & 1) << 10) + lane * 16;
                int off  = (row << 11) + (colb ^ ((row & 15) << 4));
                *(u32x4*)(hs_base + off) = h[j];
            }
            asm volatile("s_waitcnt lgkmcnt(0)" ::: "memory");
            __builtin_amdgcn_s_barrier();            // barrier A: Hs ready

            // ---- K-eighth: 8 A-reads, 16 MFMAs (each read feeds BOTH tiles) ----
            f32x16 acc0 = {}, acc1 = {};
            const char* hrow = hs_base + (ln << 11);
#pragma unroll
            for (int kk = 0; kk < 8; ++kk) {
                int cb = ((wv << 8) + (kk << 5) + (lh << 4)) ^ rxor;
                bf16x8 a = *(const bf16x8*)(hrow + cb);
                acc0 = __builtin_amdgcn_mfma_f32_32x32x16_bf16(a, br0[kk], acc0, 0, 0, 0);
                acc1 = __builtin_amdgcn_mfma_f32_32x32x16_bf16(a, br1[kk], acc1, 0, 0, 0);
            }

            // ---- dump partials: SlT[ks][b][col] (conflict-free) ----
#pragma unroll
            for (int rg = 0; rg < 4; ++rg)
#pragma unroll
                for (int rr = 0; rr < 4; ++rr) {
                    const int bb = rg * 8 + lh * 4 + rr;
                    SlT[wv][bb][ln]      = acc0[rg * 4 + rr];
                    SlT[wv][bb][32 + ln] = acc1[rg * 4 + rr];
                }
            asm volatile("s_waitcnt lgkmcnt(0)" ::: "memory");
            __builtin_amdgcn_s_barrier();            // barrier B: SlT ready
        }

        // ---- epilogue: ONE output (batch, unit uu) per thread ----
        f32x4 gv = ga;                               // gates i,f,g,o of unit uu
        if (t > 0) {
#pragma unroll
            for (int ks = 0; ks < 8; ++ks)
                gv += *(const f32x4*)&SlT[ks][batch][uu * 4];
        }
        float cn = sigf(gv[1]) * cs + sigf(gv[0]) * tanh_fast(gv[2]);
        cs = cn;
        float hv = sigf(gv[3]) * tanh_fast(cn);

        // pack h pairs via in-wave LDS bounce (Ht rows 4b per wave: in-wave only)
        Ht[batch][uu] = f2bf(hv);
        asm volatile("s_waitcnt lgkmcnt(0)" ::: "memory");
        if ((uu & 1) == 0) {
            u32 packed = *(const u32*)&Ht[batch][uu];
            store_u32_coh((u32*)(hb + (size_t)(t + 1) * (BATCH * HID)
                                    + (size_t)batch * HID + wg * 16 + uu), packed);
        }

        // off the critical path: G prefetch for step t+1 + out-store
        if (t + 1 < T_STEPS)
            ga = *(const f32x4*)(Gp + ((size_t)wg * MROWS + (size_t)(t + 1) * 32 + batch) * 64
                                 + uu * 4);
        out[((size_t)t * BATCH + batch) * HID + wg * 16 + uu] = hv;
        // no end-of-loop barrier: stage(t+1) Hs writes are sentinel-gated behind
        // every wave's h-store(t+1), which follows its SlT/Hs reads of step t.
    }
}

// ---------------- launch ----------------

extern "C" void kernel_launch(void* const* d_in, const int* in_sizes, int n_in,
                              void* d_out, int out_size, void* d_ws, size_t ws_size,
                              hipStream_t stream) {
    const float* x  = (const float*)d_in[0];   // T*B*D
    const float* Wx = (const float*)d_in[1];   // D x 4H
    const float* Wh = (const float*)d_in[2];   // H x 4H
    const float* b  = (const float*)d_in[3];   // 4H
    float* out = (float*)d_out;

    // workspace layout (bytes)
    char* ws = (char*)d_ws;
    const size_t OFF_XBF  = 0;                       // 8 MB  (4096x1024 bf16)
    const size_t OFF_WXT  = 8ull  << 20;             // 8 MB  (gate-minor rows)
    const size_t OFF_WHT  = 16ull << 20;             // 8 MB  (gate-minor rows)
    const size_t OFF_G    = 24ull << 20;             // 64 MB (64x4096x64 fp32)
    const size_t OFF_HB   = 88ull << 20;             // 129 * 64 KB = 8.0625 MB
    const size_t NEEDED   = OFF_HB + (size_t)(T_STEPS + 1) * BATCH * HID * 2;
    if (ws_size < NEEDED) return;  // loud failure (output stays poisoned)

    unsigned short* xbf = (unsigned short*)(ws + OFF_XBF);
    unsigned short* WxT = (unsigned short*)(ws + OFF_WXT);
    unsigned short* WhT = (unsigned short*)(ws + OFF_WHT);
    float*          Gp  = (float*)(ws + OFF_G);
    unsigned short* hb  = (unsigned short*)(ws + OFF_HB);

    // prep: ONE kernel (cast + hb fill + both weight transposes)
    const int HBW = (T_STEPS + 1) * BATCH * HID / 2;    // u32 words in hb
    prep_all<<<PREP_NBLK, 256, 0, stream>>>(x, xbf, (u32*)hb, HBW, Wx, WxT, Wh, WhT);

    // phase 1: all-timestep input GEMM (async-staged, XCD-swizzled, coalesced out)
    gemm_xw<<<dim3(32, 32), 256, 0, stream>>>(xbf, WxT, b, Gp);

    // phase 2: persistent recurrence (exact R3/R8/R10 structure)
    lstm_rec<<<NWGR, 512, 0, stream>>>(WhT, Gp, hb, out);
}